// Round 1
// baseline (2691.989 us; speedup 1.0000x reference)
//
#include <hip/hip_runtime.h>

typedef unsigned short u16;
typedef __attribute__((ext_vector_type(8))) short short8;
typedef __attribute__((ext_vector_type(4))) float f32x4;

// ---------- helpers ----------
__device__ __forceinline__ u16 f2bf(float x) {
    unsigned u = __float_as_uint(x);
    u = (u + 0x7FFFu + ((u >> 16) & 1u)) >> 16;
    return (u16)u;
}

__device__ __forceinline__ void gload_lds16(const u16* g, u16* l) {
    __builtin_amdgcn_global_load_lds((const __attribute__((address_space(1))) void*)g,
                                     (__attribute__((address_space(3))) void*)l, 16, 0, 0);
}

// ---------- fp32 -> bf16 convert ----------
__global__ __launch_bounds__(256) void cvt_bf16_k(const float* __restrict__ in,
                                                  u16* __restrict__ out, int n4) {
    int i = blockIdx.x * 256 + threadIdx.x;
    if (i >= n4) return;
    float4 v = ((const float4*)in)[i];
    ushort4 o;
    o.x = f2bf(v.x); o.y = f2bf(v.y); o.z = f2bf(v.z); o.w = f2bf(v.w);
    ((ushort4*)out)[i] = o;
}

// ---------- W_hh [4096][1024] -> WhhT [1024][4096] ----------
__global__ __launch_bounds__(256) void transpose_f32(const float* __restrict__ in,
                                                     float* __restrict__ out, int R, int C) {
    __shared__ float tile[32][33];
    int c0 = blockIdx.x * 32, r0 = blockIdx.y * 32;
    int tx = threadIdx.x & 31, ty = threadIdx.x >> 5;
#pragma unroll
    for (int u = 0; u < 4; ++u)
        tile[ty + u * 8][tx] = in[(size_t)(r0 + ty + u * 8) * C + c0 + tx];
    __syncthreads();
#pragma unroll
    for (int u = 0; u < 4; ++u)
        out[(size_t)(c0 + ty + u * 8) * R + r0 + tx] = tile[tx][ty + u * 8];
}

// ---------- embedding + relu -> bf16 A-matrix rows m = t*64+b ----------
__global__ __launch_bounds__(256) void embed_relu(const int* __restrict__ tgt,
                                                  const float* __restrict__ emb,
                                                  u16* __restrict__ x_bf) {
    int t = blockIdx.x, b = blockIdx.y;
    int tok = (t == 0) ? 0 : tgt[b * 60 + t - 1];
    const float4* src = (const float4*)(emb + (size_t)tok * 1024);
    ushort4* dst = (ushort4*)(x_bf + (size_t)(t * 64 + b) * 1024);
    float4 v = src[threadIdx.x];
    ushort4 o;
    o.x = f2bf(fmaxf(v.x, 0.f)); o.y = f2bf(fmaxf(v.y, 0.f));
    o.z = f2bf(fmaxf(v.z, 0.f)); o.w = f2bf(fmaxf(v.w, 0.f));
    dst[threadIdx.x] = o;
}

// ---------- h0/c0 [b][j] -> transposed state [j][b] ----------
__global__ __launch_bounds__(256) void init_hc(const float* __restrict__ h0,
                                               const float* __restrict__ c0,
                                               float* __restrict__ hT, float* __restrict__ cT) {
    int i = blockIdx.x * 256 + threadIdx.x;  // 65536, b fast
    int j = i >> 6, b = i & 63;
    hT[i] = h0[b * 1024 + j];
    cT[i] = c0[b * 1024 + j];
}

// ---------- bf16 MFMA GEMM, A[M,K] @ B^T[N,K], K=1024, 128x128 tiles ----------
// EPI=0: out = xWT[t][n][b] (+b_ih+b_hh);  EPI=1: out = logits[b][t][v] (+b_out)
template <int EPI>
__global__ __launch_bounds__(256) void gemm_bt(const u16* __restrict__ A,
                                               const u16* __restrict__ Bm,
                                               const float* __restrict__ bias0,
                                               const float* __restrict__ bias1,
                                               float* __restrict__ out) {
    constexpr int K = 1024;
    __shared__ u16 lds_a[128 * 32];
    __shared__ u16 lds_b[128 * 32];
    const int tid = threadIdx.x;
    const int lane = tid & 63, wave = tid >> 6;
    const int tileM = blockIdx.y * 128;
    const int tileN = blockIdx.x * 128;
    const int wm = (wave >> 1) * 64, wn = (wave & 1) * 64;

    const int sRow = wave * 32 + (lane >> 2);
    const int sCol = (lane & 3) * 8;
    const u16* gA = A + (size_t)(tileM + sRow) * K + sCol;
    const u16* gB = Bm + (size_t)(tileN + sRow) * K + sCol;
    u16* lA = lds_a + sRow * 32 + sCol;
    u16* lB = lds_b + sRow * 32 + sCol;

    f32x4 acc[4][4] = {};
    const int fr = lane & 15, fq = lane >> 4;

    for (int k0 = 0; k0 < K; k0 += 32) {
        gload_lds16(gA + k0, lA);
        gload_lds16(gA + k0 + 16 * K, lA + 16 * 32);
        gload_lds16(gB + k0, lB);
        gload_lds16(gB + k0 + 16 * K, lB + 16 * 32);
        __syncthreads();
        short8 af[4], bfv[4];
#pragma unroll
        for (int i = 0; i < 4; ++i)
            af[i] = *(const short8*)&lds_a[(wm + i * 16 + fr) * 32 + fq * 8];
#pragma unroll
        for (int j = 0; j < 4; ++j)
            bfv[j] = *(const short8*)&lds_b[(wn + j * 16 + fr) * 32 + fq * 8];
#pragma unroll
        for (int i = 0; i < 4; ++i)
#pragma unroll
            for (int j = 0; j < 4; ++j)
                acc[i][j] = __builtin_amdgcn_mfma_f32_16x16x32_bf16(af[i], bfv[j], acc[i][j], 0, 0, 0);
        __syncthreads();
    }
    const int cr = fq * 4, cc = fr;
#pragma unroll
    for (int i = 0; i < 4; ++i) {
#pragma unroll
        for (int j = 0; j < 4; ++j) {
            int col = tileN + wn + j * 16 + cc;
            float bb;
            if (EPI == 0) bb = bias0[col] + bias1[col];
            else          bb = bias0[col];
#pragma unroll
            for (int r = 0; r < 4; ++r) {
                int row = tileM + wm + i * 16 + cr + r;  // row = t*64 + b
                float v = acc[i][j][r] + bb;
                if (EPI == 0) {
                    out[((size_t)(row >> 6) * 4096 + col) * 64 + (row & 63)] = v;
                } else {
                    out[((size_t)(row & 63) * 60 + (row >> 6)) * 32000 + col] = v;
                }
            }
        }
    }
}

// ---------- recurrent partial: part[kc][n][b] = sum_{k in chunk} h[b][k]*Whh[n][k] ----------
__global__ __launch_bounds__(256) void gates_partial(const float* __restrict__ hT,
                                                     const float* __restrict__ WhhT,
                                                     float* __restrict__ part) {
    __shared__ float shT[32][64];
    __shared__ float swT[32][256];
    const int tid = threadIdx.x;
    const int n0 = blockIdx.x * 256;
    const int kc = blockIdx.y;  // 0..15, each 64 k
    float acc[8][8] = {};
    const int tb = (tid & 7) * 8;
    const int tn = (tid >> 3) * 8;
    for (int kk = 0; kk < 2; ++kk) {
        const int k0 = kc * 64 + kk * 32;
#pragma unroll
        for (int r = 0; r < 2; ++r) {  // stage shT: 512 float4
            int f4 = r * 256 + tid;
            int b4 = (f4 & 15) * 4, k = f4 >> 4;
            *(float4*)&shT[k][b4] = *(const float4*)&hT[(size_t)(k0 + k) * 64 + b4];
        }
#pragma unroll
        for (int r = 0; r < 8; ++r) {  // stage swT: 2048 float4
            int f4 = r * 256 + tid;
            int n4 = (f4 & 63) * 4, k = f4 >> 6;
            *(float4*)&swT[k][n4] = *(const float4*)&WhhT[(size_t)(k0 + k) * 4096 + n0 + n4];
        }
        __syncthreads();
#pragma unroll 2
        for (int k = 0; k < 32; ++k) {
            float4 h0v = *(const float4*)&shT[k][tb];
            float4 h1v = *(const float4*)&shT[k][tb + 4];
            float4 w0v = *(const float4*)&swT[k][tn];
            float4 w1v = *(const float4*)&swT[k][tn + 4];
            float hv[8] = {h0v.x, h0v.y, h0v.z, h0v.w, h1v.x, h1v.y, h1v.z, h1v.w};
            float wv[8] = {w0v.x, w0v.y, w0v.z, w0v.w, w1v.x, w1v.y, w1v.z, w1v.w};
#pragma unroll
            for (int u = 0; u < 8; ++u)
#pragma unroll
                for (int v = 0; v < 8; ++v) acc[u][v] += hv[u] * wv[v];
        }
        __syncthreads();
    }
    float* p = part + ((size_t)kc * 4096 + n0) * 64;
#pragma unroll
    for (int v = 0; v < 8; ++v) {
        float4 o0, o1;
        o0.x = acc[0][v]; o0.y = acc[1][v]; o0.z = acc[2][v]; o0.w = acc[3][v];
        o1.x = acc[4][v]; o1.y = acc[5][v]; o1.z = acc[6][v]; o1.w = acc[7][v];
        *(float4*)&p[(size_t)(tn + v) * 64 + tb] = o0;
        *(float4*)&p[(size_t)(tn + v) * 64 + tb + 4] = o1;
    }
}

// ---------- gate nonlinearities + state update ----------
__global__ __launch_bounds__(256) void lstm_update(const float* __restrict__ xWT,
                                                   const float* __restrict__ part,
                                                   float* __restrict__ hT, float* __restrict__ cT,
                                                   u16* __restrict__ hs_bf, int t) {
    const int tid = threadIdx.x;
    const int b = tid & 63;
    const int j = blockIdx.x * 4 + (tid >> 6);  // 0..1023
    const float* xw = xWT + (size_t)t * 4096 * 64;
    float g[4];
#pragma unroll
    for (int q = 0; q < 4; ++q) {
        int n = j + q * 1024;
        float s = xw[(size_t)n * 64 + b];
#pragma unroll
        for (int kc = 0; kc < 16; ++kc) s += part[((size_t)kc * 4096 + n) * 64 + b];
        g[q] = s;
    }
    float ig = 1.f / (1.f + __expf(-g[0]));
    float fg = 1.f / (1.f + __expf(-g[1]));
    float gg = tanhf(g[2]);
    float og = 1.f / (1.f + __expf(-g[3]));
    float c = fg * cT[j * 64 + b] + ig * gg;
    float h = og * tanhf(c);
    cT[j * 64 + b] = c;
    hT[j * 64 + b] = h;
    hs_bf[(size_t)(t * 64 + b) * 1024 + j] = f2bf(h);
}

// ---------- log_softmax: per-row (max, log-sum-exp) ----------
__global__ __launch_bounds__(256) void softmax_stats(const float* __restrict__ logits,
                                                     float* __restrict__ stats) {
    const int row = blockIdx.x;
    const float* x = logits + (size_t)row * 32000;
    float m = -3.4e38f, s = 0.f;
    for (int i = threadIdx.x; i < 32000; i += 256) {
        float v = x[i];
        float mn = fmaxf(m, v);
        s = s * __expf(m - mn) + __expf(v - mn);
        m = mn;
    }
    __shared__ float sm[256], ss[256];
    sm[threadIdx.x] = m; ss[threadIdx.x] = s;
    __syncthreads();
    for (int off = 128; off > 0; off >>= 1) {
        if (threadIdx.x < off) {
            float m2 = sm[threadIdx.x + off], s2 = ss[threadIdx.x + off];
            float m1 = sm[threadIdx.x], s1 = ss[threadIdx.x];
            float M = fmaxf(m1, m2);
            ss[threadIdx.x] = s1 * __expf(m1 - M) + s2 * __expf(m2 - M);
            sm[threadIdx.x] = M;
        }
        __syncthreads();
    }
    if (threadIdx.x == 0) stats[row] = sm[0] + __logf(ss[0]);
}

__global__ __launch_bounds__(256) void softmax_apply(float* __restrict__ logits,
                                                     const float* __restrict__ stats) {
    const int row = blockIdx.x;
    const float d = stats[row];
    float4* x = (float4*)(logits + (size_t)row * 32000);
    for (int i = threadIdx.x; i < 8000; i += 256) {
        float4 v = x[i];
        v.x -= d; v.y -= d; v.z -= d; v.w -= d;
        x[i] = v;
    }
}

// ---------- final h,c -> d_out tail ----------
__global__ __launch_bounds__(256) void copy_hc(const float* __restrict__ hT,
                                               const float* __restrict__ cT,
                                               float* __restrict__ out) {
    int i = blockIdx.x * 256 + threadIdx.x;  // 0..65535
    int b = i >> 10, j = i & 1023;
    out[i] = hT[j * 64 + b];
    out[65536 + i] = cT[j * 64 + b];
}

extern "C" void kernel_launch(void* const* d_in, const int* in_sizes, int n_in,
                              void* d_out, int out_size, void* d_ws, size_t ws_size,
                              hipStream_t stream) {
    const float* h0 = (const float*)d_in[1];
    const float* c0 = (const float*)d_in[2];
    const int* tgt = (const int*)d_in[3];
    const float* emb = (const float*)d_in[4];
    const float* Wih = (const float*)d_in[5];
    const float* Whh = (const float*)d_in[6];
    const float* bih = (const float*)d_in[7];
    const float* bhh = (const float*)d_in[8];
    const float* Wout = (const float*)d_in[9];
    const float* bout = (const float*)d_in[10];
    float* out = (float*)d_out;

    char* ws = (char*)d_ws;
    size_t o = 0;
    auto al = [&](size_t bytes) { size_t r = o; o += (bytes + 255) & ~255UL; return r; };
    u16* wih_bf = (u16*)(ws + al(4096ul * 1024 * 2));
    u16* wout_bf = (u16*)(ws + al(32000ul * 1024 * 2));
    u16* x_bf = (u16*)(ws + al(3840ul * 1024 * 2));
    u16* hs_bf = (u16*)(ws + al(3840ul * 1024 * 2));
    float* xWT = (float*)(ws + al(60ul * 4096 * 64 * 4));
    float* WhhT = (float*)(ws + al(4096ul * 1024 * 4));
    float* hT = (float*)(ws + al(65536ul * 4));
    float* cT = (float*)(ws + al(65536ul * 4));
    float* part = (float*)(ws + al(16ul * 4096 * 64 * 4));
    float* stats = (float*)(ws + al(3840ul * 4));

    cvt_bf16_k<<<(4096 * 1024 / 4 + 255) / 256, 256, 0, stream>>>(Wih, wih_bf, 4096 * 1024 / 4);
    cvt_bf16_k<<<(32000 * 1024 / 4 + 255) / 256, 256, 0, stream>>>(Wout, wout_bf, 32000 * 1024 / 4);
    transpose_f32<<<dim3(32, 128), 256, 0, stream>>>(Whh, WhhT, 4096, 1024);
    embed_relu<<<dim3(60, 64), 256, 0, stream>>>(tgt, emb, x_bf);
    init_hc<<<256, 256, 0, stream>>>(h0, c0, hT, cT);
    // xW[t,b,n] = relu(emb) @ W_ih^T + (b_ih + b_hh), stored transposed [t][n][b]
    gemm_bt<0><<<dim3(32, 30), 256, 0, stream>>>(x_bf, wih_bf, bih, bhh, xWT);
    for (int t = 0; t < 60; ++t) {
        gates_partial<<<dim3(16, 16), 256, 0, stream>>>(hT, WhhT, part);
        lstm_update<<<256, 256, 0, stream>>>(xWT, part, hT, cT, hs_bf, t);
    }
    // logits[b][t][v] = hs @ W_out^T + b_out
    gemm_bt<1><<<dim3(250, 30), 256, 0, stream>>>(hs_bf, wout_bf, bout, bout, out);
    softmax_stats<<<3840, 256, 0, stream>>>(out, stats);
    softmax_apply<<<3840, 256, 0, stream>>>(out, stats);
    copy_hc<<<256, 256, 0, stream>>>(hT, cT, out + 122880000ul);
}